// Round 6
// baseline (545.360 us; speedup 1.0000x reference)
//
#include <hip/hip_runtime.h>

#define TLEN 300
#define THETA 10.0f
#define REF_DECAY 0.36787944117144233f

// FIR LDS row geometry: 101 quads (404 floats) per row. Data at quads 25..99
// (words 100..399), zero pads at quads 0..24 and quad 100. Odd quad stride ->
// <=2-way bank aliasing (free) for all b128 patterns used.
#define QS 101
#define DQ 25

// ---------------- eps table: eps[k] = (k/10) * exp(1 - k/10), k=0..99; [100..103]=0 ----
__global__ void eps_init_kernel(float* __restrict__ eps) {
  int k = threadIdx.x;
  if (k < 104) eps[k] = 0.f;
  if (k < 100) {
    float a = (float)k / 10.0f;
    eps[k] = a * expf(1.0f - a);
  }
}

// 4-tap x 8-output FMA block; statement order identical to prior (verified) rounds.
#define FIRSTEP(e, A, B, C)                                                              \
  acc[0] += e.x * B.x; acc[1] += e.x * B.y; acc[2] += e.x * B.z; acc[3] += e.x * B.w;    \
  acc[4] += e.x * C.x; acc[5] += e.x * C.y; acc[6] += e.x * C.z; acc[7] += e.x * C.w;    \
  acc[0] += e.y * A.w; acc[1] += e.y * B.x; acc[2] += e.y * B.y; acc[3] += e.y * B.z;    \
  acc[4] += e.y * B.w; acc[5] += e.y * C.x; acc[6] += e.y * C.y; acc[7] += e.y * C.z;    \
  acc[0] += e.z * A.z; acc[1] += e.z * A.w; acc[2] += e.z * B.x; acc[3] += e.z * B.y;    \
  acc[4] += e.z * B.z; acc[5] += e.z * B.w; acc[6] += e.z * C.x; acc[7] += e.z * C.y;    \
  acc[0] += e.w * A.y; acc[1] += e.w * A.z; acc[2] += e.w * A.w; acc[3] += e.w * B.x;    \
  acc[4] += e.w * B.y; acc[5] += e.w * B.z; acc[6] += e.w * B.w; acc[7] += e.w * C.x;

// ---------------- 100-tap FIR: 8 outputs/thread, bounded register pressure ----------------
// acc[j] = sum_k eps[k] * x[8l + j - k], k ascending (identical summation order).
__device__ __forceinline__ void fir100s(const float4* __restrict__ row4, int l,
                                        const float* __restrict__ epss, float acc[8]) {
  const int qB = DQ + 2 * l;
  float4 A = row4[qB - 1];
  float4 B = row4[qB];
  float4 C = row4[qB + 1];
#pragma unroll
  for (int j = 0; j < 8; ++j) acc[j] = 0.f;
#pragma unroll 1
  for (int kg0 = 0; kg0 < 80; kg0 += 20) {
    const float* ep = epss + kg0;
    const float4* ap = row4 + (qB - 2 - (kg0 >> 2));
#pragma unroll
    for (int kk = 0; kk < 5; ++kk) {
      const float4 e = *reinterpret_cast<const float4*>(ep + 4 * kk);
      FIRSTEP(e, A, B, C);
      C = B; B = A;
      A = ap[-kk];
    }
    __builtin_amdgcn_sched_barrier(0);  // cap in-flight loads (VGPR control)
  }
#pragma unroll
  for (int kk = 0; kk < 5; ++kk) {
    const float4 e = *reinterpret_cast<const float4*>(epss + 80 + 4 * kk);
    FIRSTEP(e, A, B, C);
    C = B; B = A;
    if (kk < 4) A = row4[qB - 22 - kk];
  }
}

// ---------------- phase-pure FIR: psp of 8 rows/block -> global ----------------
__global__ __launch_bounds__(320, 4) void fir_kernel(const float* __restrict__ in,
                                                     float* __restrict__ out,
                                                     const float* __restrict__ epsg) {
  __shared__ float4 xs[8 * QS];
  __shared__ float epss[104];
  const int tid = threadIdx.x;
  const long row0 = (long)blockIdx.x * 8;
  if (tid < 104) epss[tid] = epsg[tid];
  if (tid < 208) {
    int r = tid / 26, k = tid - r * 26;
    int q = (k < 25) ? k : 100;
    xs[r * QS + q] = make_float4(0.f, 0.f, 0.f, 0.f);
  }
  for (int i = tid; i < 600; i += 320) {
    int r = i / 75, q = i - r * 75;
    xs[r * QS + DQ + q] = *reinterpret_cast<const float4*>(in + (row0 + r) * TLEN + 4 * q);
  }
  __syncthreads();
  if (tid < 304) {
    int r = tid & 7, l = tid >> 3;
    float acc[8];
    fir100s(xs + r * QS, l, epss, acc);
    long off = (row0 + r) * TLEN + 8 * l;
    *reinterpret_cast<float4*>(out + off) = make_float4(acc[0], acc[1], acc[2], acc[3]);
    if (l < 37)
      *reinterpret_cast<float4*>(out + off + 4) = make_float4(acc[4], acc[5], acc[6], acc[7]);
  }
}

// ---------------- FIR with fused per-channel delay gather on input (L7) ----------------
__global__ __launch_bounds__(320, 4) void fir_delay_kernel(const float* __restrict__ in,
                                                           float* __restrict__ out,
                                                           const float* __restrict__ epsg,
                                                           const float* __restrict__ dly) {
  __shared__ float4 xs[8 * QS];
  __shared__ float epss[104];
  const int tid = threadIdx.x;
  const long row0 = (long)blockIdx.x * 8;
  if (tid < 104) epss[tid] = epsg[tid];
  if (tid < 208) {
    int r = tid / 26, k = tid - r * 26;
    int q = (k < 25) ? k : 100;
    xs[r * QS + q] = make_float4(0.f, 0.f, 0.f, 0.f);
  }
  for (int i = tid; i < 600; i += 320) {
    int r = i / 75, q = i - r * 75;
    long row = row0 + r;
    float dd = dly[(int)(row & 511)];  // C = 512
    const float* rowp = in + row * TLEN;
    float4 o;
    float* op = &o.x;
#pragma unroll
    for (int j = 0; j < 4; ++j) {
      int t = 4 * q + j;
      float src = (float)t - dd;
      float fi = floorf(src);
      int i0 = (int)fi;  // in [-4, 299]
      float wf = src - fi;
      float v0 = (i0 >= 0 && i0 < TLEN) ? rowp[min(max(i0, 0), TLEN - 1)] : 0.f;
      float v1 = (i0 + 1 >= 0 && i0 + 1 < TLEN) ? rowp[min(max(i0 + 1, 0), TLEN - 1)] : 0.f;
      op[j] = v0 * (1.f - wf) + v1 * wf;
    }
    xs[r * QS + DQ + q] = o;
  }
  __syncthreads();
  if (tid < 304) {
    int r = tid & 7, l = tid >> 3;
    float acc[8];
    fir100s(xs + r * QS, l, epss, acc);
    long off = (row0 + r) * TLEN + 8 * l;
    *reinterpret_cast<float4*>(out + off) = make_float4(acc[0], acc[1], acc[2], acc[3]);
    if (l < 37)
      *reinterpret_cast<float4*>(out + off + 4) = make_float4(acc[4], acc[5], acc[6], acc[7]);
  }
}

// ---------------- in-place refractory scan: 1 row/lane, direct global, 4-deep prefetch ----
__global__ __launch_bounds__(64) void scan_kernel(float* __restrict__ u, long rows) {
  long row = (long)blockIdx.x * 64 + threadIdx.x;
  if (row >= rows) return;
  float* p = u + row * TLEN;
  float4 q0 = *reinterpret_cast<const float4*>(p);
  float4 q1 = *reinterpret_cast<const float4*>(p + 4);
  float4 q2 = *reinterpret_cast<const float4*>(p + 8);
  float4 q3 = *reinterpret_cast<const float4*>(p + 12);
  float ref = 0.f;
#pragma unroll 4
  for (int c4 = 0; c4 < 75; ++c4) {
    float4 u4 = q0;
    q0 = q1; q1 = q2; q2 = q3;
    if (c4 < 71) q3 = *reinterpret_cast<const float4*>(p + 4 * (c4 + 4));
    float v, sp;
    v = u4.x + ref - THETA; sp = (v >= 0.f) ? 1.f : 0.f; u4.x = sp; ref = REF_DECAY * ref - 20.0f * sp;
    v = u4.y + ref - THETA; sp = (v >= 0.f) ? 1.f : 0.f; u4.y = sp; ref = REF_DECAY * ref - 20.0f * sp;
    v = u4.z + ref - THETA; sp = (v >= 0.f) ? 1.f : 0.f; u4.z = sp; ref = REF_DECAY * ref - 20.0f * sp;
    v = u4.w + ref - THETA; sp = (v >= 0.f) ? 1.f : 0.f; u4.w = sp; ref = REF_DECAY * ref - 20.0f * sp;
    *reinterpret_cast<float4*>(p + 4 * c4) = u4;
  }
}

// ---------------- fc1 4-partial sum + scan -> spikes S5 ----------------
__global__ __launch_bounds__(64) void scan_reduce4_kernel(const float* __restrict__ part,
                                                          float* __restrict__ s) {
  long row = (long)blockIdx.x * 64 + threadIdx.x;  // 2048 rows
  const float* p = part + row * TLEN;
  float* o = s + row * TLEN;
  float ref = 0.f;
#pragma unroll 4
  for (int c4 = 0; c4 < 75; ++c4) {
    const float4 v0 = *reinterpret_cast<const float4*>(p + 4 * c4);
    const float4 v1 = *reinterpret_cast<const float4*>(p + 614400 + 4 * c4);
    const float4 v2 = *reinterpret_cast<const float4*>(p + 1228800 + 4 * c4);
    const float4 v3 = *reinterpret_cast<const float4*>(p + 1843200 + 4 * c4);
    float4 u4;
    u4.x = (v0.x + v1.x) + (v2.x + v3.x);
    u4.y = (v0.y + v1.y) + (v2.y + v3.y);
    u4.z = (v0.z + v1.z) + (v2.z + v3.z);
    u4.w = (v0.w + v1.w) + (v2.w + v3.w);
    float v, sp;
    v = u4.x + ref - THETA; sp = (v >= 0.f) ? 1.f : 0.f; u4.x = sp; ref = REF_DECAY * ref - 20.0f * sp;
    v = u4.y + ref - THETA; sp = (v >= 0.f) ? 1.f : 0.f; u4.y = sp; ref = REF_DECAY * ref - 20.0f * sp;
    v = u4.z + ref - THETA; sp = (v >= 0.f) ? 1.f : 0.f; u4.z = sp; ref = REF_DECAY * ref - 20.0f * sp;
    v = u4.w + ref - THETA; sp = (v >= 0.f) ? 1.f : 0.f; u4.w = sp; ref = REF_DECAY * ref - 20.0f * sp;
    *reinterpret_cast<float4*>(o + 4 * c4) = u4;
  }
}

// ---------------- 4x4 sum-pool on raw input (float4 over t), scale 0.6875 ----------------
__global__ __launch_bounds__(256) void pool4_kernel(const float* __restrict__ in,
                                                    float* __restrict__ out) {
  int idx = blockIdx.x * 256 + threadIdx.x;  // quad index
  if (idx >= 153600) return;
  int tq = idx % 75;
  int rest = idx / 75;
  int x = rest & 31; rest >>= 5;
  int y = rest & 31; rest >>= 5;  // rest = bc (0..7)
  const float* base = in + ((long)(rest * 128 + y * 4) * 128 + x * 4) * TLEN + tq * 4;
  float4 s = {0.f, 0.f, 0.f, 0.f};
#pragma unroll
  for (int dy = 0; dy < 4; ++dy)
#pragma unroll
    for (int dx = 0; dx < 4; ++dx) {
      float4 v = *reinterpret_cast<const float4*>(base + (dy * 128 + dx) * TLEN);
      s.x += v.x; s.y += v.y; s.z += v.z; s.w += v.w;
    }
  s.x *= 0.6875f; s.y *= 0.6875f; s.z *= 0.6875f; s.w *= 0.6875f;
  *reinterpret_cast<float4*>(out + ((long)(rest * 32 + y) * 32 + x) * TLEN + tq * 4) = s;
}

// ---------------- fused delay + 2x2 pool on spike tensor, scale 2.75 ----------------
__global__ __launch_bounds__(256) void pool2_delay_kernel(const float* __restrict__ in,
                                                          const float* __restrict__ d,
                                                          float* __restrict__ out,
                                                          int C, int HO, int WO, int total) {
  int idx = blockIdx.x * 256 + threadIdx.x;
  if (idx >= total) return;
  int t = idx % TLEN;
  int rest = idx / TLEN;
  int x = rest % WO; rest /= WO;
  int y = rest % HO; rest /= HO;
  int c = rest % C;
  int b = rest / C;
  float dd = d[c];
  float src = (float)t - dd;
  float fi = floorf(src);
  int i0 = (int)fi;
  float wf = src - fi;
  const float* base = in + (((long)(b * C + c) * (2 * HO) + 2 * y) * (2 * WO) + 2 * x) * TLEN;
  long rs = (long)(2 * WO) * TLEN;
  bool ok0 = (i0 >= 0) && (i0 < TLEN);
  bool ok1 = (i0 + 1 >= 0) && (i0 + 1 < TLEN);
  int j0 = min(max(i0, 0), TLEN - 1);
  int j1 = min(max(i0 + 1, 0), TLEN - 1);
  float s0 = 0.f, s1 = 0.f;
#pragma unroll
  for (int dy = 0; dy < 2; ++dy)
#pragma unroll
    for (int dx = 0; dx < 2; ++dx) {
      const float* pp = base + dy * rs + dx * TLEN;
      s0 += ok0 ? pp[j0] : 0.f;
      s1 += ok1 ? pp[j1] : 0.f;
    }
  out[idx] = (s0 * (1.f - wf) + s1 * wf) * 2.75f;
}

// ---------------- conv1: 2->16 ch, 5x5, pad 2, 32x32, float4 staging ----------------
__global__ __launch_bounds__(256) void conv1_kernel(const float* __restrict__ in,
                                                    const float* __restrict__ w,
                                                    float* __restrict__ out) {
  __shared__ float xl[11520];  // [c2][dy5][x36][t32]
  const int tid = threadIdx.x;
  const int t0 = blockIdx.x * 32;
  const int y = blockIdx.y;
  const int b = blockIdx.z;
  for (int i = tid; i < 2880; i += 256) {
    int tq = i & 7;
    int rest = i >> 3;
    int xp = rest % 36;
    int r2 = rest / 36;
    int dy = r2 % 5;
    int c = r2 / 5;
    int yy = y + dy - 2, xx = xp - 2, t = t0 + tq * 4;
    float4 v = {0.f, 0.f, 0.f, 0.f};
    if (yy >= 0 && yy < 32 && xx >= 0 && xx < 32 && t < TLEN)
      v = *reinterpret_cast<const float4*>(
          in + ((long)((b * 2 + c) * 32 + yy) * 32 + xx) * TLEN + t);
    *reinterpret_cast<float4*>(&xl[rest * 32 + tq * 4]) = v;
  }
  __syncthreads();
  const int tg = tid & 7;
  const int x = tid >> 3;
  float acc[16][4];
#pragma unroll
  for (int o = 0; o < 16; ++o) { acc[o][0] = acc[o][1] = acc[o][2] = acc[o][3] = 0.f; }
  for (int c = 0; c < 2; ++c)
#pragma unroll
    for (int dy = 0; dy < 5; ++dy)
#pragma unroll
      for (int kx = 0; kx < 5; ++kx) {
        const float4 xv = *reinterpret_cast<const float4*>(
            &xl[((c * 5 + dy) * 36 + x + kx) * 32 + tg * 4]);
        const float* wp = w + (c * 5 + dy) * 5 + kx;
#pragma unroll
        for (int o = 0; o < 16; ++o) {
          float wsc = wp[o * 50];
          acc[o][0] += wsc * xv.x; acc[o][1] += wsc * xv.y;
          acc[o][2] += wsc * xv.z; acc[o][3] += wsc * xv.w;
        }
      }
  const int t = t0 + tg * 4;
  if (t < TLEN) {
#pragma unroll
    for (int o = 0; o < 16; ++o) {
      float4 res; res.x = acc[o][0]; res.y = acc[o][1]; res.z = acc[o][2]; res.w = acc[o][3];
      *reinterpret_cast<float4*>(&out[((long)((b * 16 + o) * 32 + y) * 32 + x) * TLEN + t]) = res;
    }
  }
}

// ---------------- conv2: 16->32 ch, 3x3, pad 1, 16x16, float4 staging ----------------
__global__ __launch_bounds__(256) void conv2_kernel(const float* __restrict__ in,
                                                    const float* __restrict__ w,
                                                    float* __restrict__ out) {
  __shared__ float xl[13824];  // [c16][dy3][x18][t16]
  const int tid = threadIdx.x;
  const int t0 = blockIdx.x * 16;
  const int y = blockIdx.y;
  const int b = blockIdx.z;
  for (int i = tid; i < 3456; i += 256) {
    int tq = i & 3;
    int rest = i >> 2;
    int xp = rest % 18;
    int r2 = rest / 18;
    int dy = r2 % 3;
    int c = r2 / 3;
    int yy = y + dy - 1, xx = xp - 1, t = t0 + tq * 4;
    float4 v = {0.f, 0.f, 0.f, 0.f};
    if (yy >= 0 && yy < 16 && xx >= 0 && xx < 16 && t < TLEN)
      v = *reinterpret_cast<const float4*>(
          in + ((long)((b * 16 + c) * 16 + yy) * 16 + xx) * TLEN + t);
    *reinterpret_cast<float4*>(&xl[rest * 16 + tq * 4]) = v;
  }
  __syncthreads();
  const int tg = tid & 3;
  const int x = (tid >> 2) & 15;
  const int oh = tid >> 6;
  float acc[8][4];
#pragma unroll
  for (int o = 0; o < 8; ++o) { acc[o][0] = acc[o][1] = acc[o][2] = acc[o][3] = 0.f; }
  for (int c = 0; c < 16; ++c)
#pragma unroll
    for (int dy = 0; dy < 3; ++dy)
#pragma unroll
      for (int kx = 0; kx < 3; ++kx) {
        const float4 xv = *reinterpret_cast<const float4*>(
            &xl[((c * 3 + dy) * 18 + x + kx) * 16 + tg * 4]);
        const float* wp = w + (c * 3 + dy) * 3 + kx;
#pragma unroll
        for (int oo = 0; oo < 8; ++oo) {
          float wsc = wp[(oh * 8 + oo) * 144];
          acc[oo][0] += wsc * xv.x; acc[oo][1] += wsc * xv.y;
          acc[oo][2] += wsc * xv.z; acc[oo][3] += wsc * xv.w;
        }
      }
  const int t = t0 + tg * 4;
  if (t < TLEN) {
#pragma unroll
    for (int oo = 0; oo < 8; ++oo) {
      int o = oh * 8 + oo;
      float4 res; res.x = acc[oo][0]; res.y = acc[oo][1]; res.z = acc[oo][2]; res.w = acc[oo][3];
      *reinterpret_cast<float4*>(&out[((long)((b * 32 + o) * 16 + y) * 16 + x) * TLEN + t]) = res;
    }
  }
}

// ---------------- fc1: k-split x4, 64x64 tiles, float4 staging, partials out ----------------
__global__ __launch_bounds__(256) void fc1_kernel(const float* __restrict__ x,
                                                  const float* __restrict__ w,
                                                  float* __restrict__ part) {
  __shared__ float wl[64][44];
  __shared__ float xlb[32][68];
  const int tid = threadIdx.x;
  const int t0 = blockIdx.x * 64;
  const int o0 = blockIdx.y * 64;
  const int b = blockIdx.z >> 2;
  const int split = blockIdx.z & 3;
  const int tx = tid & 15, ty = tid >> 4;
  float acc[4][4];
#pragma unroll
  for (int i = 0; i < 4; ++i)
#pragma unroll
    for (int j = 0; j < 4; ++j) acc[i][j] = 0.f;
  const int kbeg = split * 512;
  for (int kc = kbeg; kc < kbeg + 512; kc += 32) {
    __syncthreads();
#pragma unroll
    for (int rr = 0; rr < 2; ++rr) {
      int i = rr * 256 + tid;
      int ol = i >> 3, kq = i & 7;
      float4 v = *reinterpret_cast<const float4*>(w + (long)(o0 + ol) * 2048 + kc + kq * 4);
      *reinterpret_cast<float4*>(&wl[ol][kq * 4]) = v;
    }
#pragma unroll
    for (int rr = 0; rr < 2; ++rr) {
      int i = rr * 256 + tid;
      int kl = i >> 4, tq = i & 15;
      int t = t0 + tq * 4;
      float4 v = {0.f, 0.f, 0.f, 0.f};
      if (t < TLEN)
        v = *reinterpret_cast<const float4*>(x + ((long)b * 2048 + kc + kl) * TLEN + t);
      *reinterpret_cast<float4*>(&xlb[kl][tq * 4]) = v;
    }
    __syncthreads();
#pragma unroll
    for (int k4 = 0; k4 < 8; ++k4) {
      float4 wq[4], xq[4];
#pragma unroll
      for (int i = 0; i < 4; ++i)
        wq[i] = *reinterpret_cast<const float4*>(&wl[ty * 4 + i][k4 * 4]);
#pragma unroll
      for (int j = 0; j < 4; ++j)
        xq[j] = *reinterpret_cast<const float4*>(&xlb[k4 * 4 + j][tx * 4]);
#pragma unroll
      for (int i = 0; i < 4; ++i) {
        float wa[4] = {wq[i].x, wq[i].y, wq[i].z, wq[i].w};
#pragma unroll
        for (int j = 0; j < 4; ++j) {
          float xa[4] = {xq[j].x, xq[j].y, xq[j].z, xq[j].w};
          acc[i][0] += wa[j] * xa[0]; acc[i][1] += wa[j] * xa[1];
          acc[i][2] += wa[j] * xa[2]; acc[i][3] += wa[j] * xa[3];
        }
      }
    }
  }
  const int t = t0 + tx * 4;
  if (t < TLEN) {
#pragma unroll
    for (int i = 0; i < 4; ++i) {
      float4 res; res.x = acc[i][0]; res.y = acc[i][1]; res.z = acc[i][2]; res.w = acc[i][3];
      *reinterpret_cast<float4*>(
          part + ((long)(split * 4 + b) * 512 + o0 + ty * 4 + i) * TLEN + t) = res;
    }
  }
}

// ---------------- fc2 + final spike scan fused, writes d_out ----------------
__global__ __launch_bounds__(320) void fc2_spike_kernel(const float* __restrict__ x,
                                                        const float* __restrict__ w,
                                                        float* __restrict__ out) {
  __shared__ float ul[304];
  int blk = blockIdx.x;
  int b = blk / 11, o = blk % 11;
  int t = threadIdx.x;
  if (t < TLEN) {
    const float* xr = x + (long)b * 512 * TLEN + t;
    const float* wr = w + o * 512;
    float a0 = 0.f, a1 = 0.f, a2 = 0.f, a3 = 0.f;
#pragma unroll 4
    for (int i = 0; i < 512; i += 4) {
      a0 += wr[i] * xr[(long)i * TLEN];
      a1 += wr[i + 1] * xr[(long)(i + 1) * TLEN];
      a2 += wr[i + 2] * xr[(long)(i + 2) * TLEN];
      a3 += wr[i + 3] * xr[(long)(i + 3) * TLEN];
    }
    ul[t] = (a0 + a1) + (a2 + a3);
  }
  __syncthreads();
  if (t == 0) {
    float ref = 0.f;
#pragma unroll 4
    for (int c = 0; c < TLEN; ++c) {
      float v = ul[c] + ref - THETA;
      float sp = (v >= 0.f) ? 1.f : 0.f;
      ul[c] = sp;
      ref = REF_DECAY * ref - 20.0f * sp;
    }
  }
  __syncthreads();
  if (t < TLEN) out[((long)b * 11 + o) * TLEN + t] = ul[t];
}

extern "C" void kernel_launch(void* const* d_in, const int* in_sizes, int n_in,
                              void* d_out, int out_size, void* d_ws, size_t ws_size,
                              hipStream_t stream) {
  const float* input = (const float*)d_in[0];
  const float* w1    = (const float*)d_in[1];
  const float* w2    = (const float*)d_in[2];
  const float* wfc1  = (const float*)d_in[3];
  const float* wfc2  = (const float*)d_in[4];
  const float* d1    = (const float*)d_in[5];
  const float* d2    = (const float*)d_in[6];
  const float* d3    = (const float*)d_in[7];

  float* ws   = (float*)d_ws;
  float* big0 = ws;                    // conv u/spikes (19.66M) / fc1 partials (2.46M)
  float* medA = big0 + 19660800;
  float* medB = medA + 4915200;
  float* fcA  = medB + 4915200;
  float* fcB  = fcA + 614400;
  float* eps  = fcB + 614400;

  hipLaunchKernelGGL(eps_init_kernel, dim3(1), dim3(128), 0, stream, eps);

  // L1: pool4 -> psp -> spike -> psp  (medA -> medB(u) -> S0 -> medA = psp(S0))
  hipLaunchKernelGGL(pool4_kernel, dim3(600), dim3(256), 0, stream, input, medA);
  hipLaunchKernelGGL(fir_kernel, dim3(1024), dim3(320), 0, stream, medA, medB, eps);
  hipLaunchKernelGGL(scan_kernel, dim3(128), dim3(64), 0, stream, medB, 8192L);
  hipLaunchKernelGGL(fir_kernel, dim3(1024), dim3(320), 0, stream, medB, medA, eps);
  // L2: conv1 -> u1 (big0); scan in-place -> S1; pool2+delay1 -> medB
  hipLaunchKernelGGL(conv1_kernel, dim3(10, 32, 4), dim3(256), 0, stream, medA, w1, big0);
  hipLaunchKernelGGL(scan_kernel, dim3(1024), dim3(64), 0, stream, big0, 65536L);
  hipLaunchKernelGGL(pool2_delay_kernel, dim3(19200), dim3(256), 0, stream,
                     big0, d1, medB, 16, 16, 16, 4915200);
  // L3: psp -> spike -> psp  (medB -> medA(u) -> S2 -> medB = psp(S2))
  hipLaunchKernelGGL(fir_kernel, dim3(2048), dim3(320), 0, stream, medB, medA, eps);
  hipLaunchKernelGGL(scan_kernel, dim3(256), dim3(64), 0, stream, medA, 16384L);
  hipLaunchKernelGGL(fir_kernel, dim3(2048), dim3(320), 0, stream, medA, medB, eps);
  // L4: conv2 -> u3 (big0); scan -> S3; pool2+delay2 -> medA
  hipLaunchKernelGGL(conv2_kernel, dim3(19, 16, 4), dim3(256), 0, stream, medB, w2, big0);
  hipLaunchKernelGGL(scan_kernel, dim3(512), dim3(64), 0, stream, big0, 32768L);
  hipLaunchKernelGGL(pool2_delay_kernel, dim3(9600), dim3(256), 0, stream,
                     big0, d2, medA, 32, 8, 8, 2457600);
  // L5: psp -> spike -> psp  (medA -> medB(u) -> S4 -> medA = psp(S4))
  hipLaunchKernelGGL(fir_kernel, dim3(1024), dim3(320), 0, stream, medA, medB, eps);
  hipLaunchKernelGGL(scan_kernel, dim3(128), dim3(64), 0, stream, medB, 8192L);
  hipLaunchKernelGGL(fir_kernel, dim3(1024), dim3(320), 0, stream, medB, medA, eps);
  // L6: fc1 -> partials (big0); sum+scan -> S5 (fcA)
  hipLaunchKernelGGL(fc1_kernel, dim3(5, 8, 16), dim3(256), 0, stream, medA, wfc1, big0);
  hipLaunchKernelGGL(scan_reduce4_kernel, dim3(32), dim3(64), 0, stream, big0, fcA);
  // L7: delay3+psp -> fcB; fc2+spike -> d_out
  hipLaunchKernelGGL(fir_delay_kernel, dim3(256), dim3(320), 0, stream, fcA, fcB, eps, d3);
  hipLaunchKernelGGL(fc2_spike_kernel, dim3(44), dim3(320), 0, stream, fcB, wfc2, (float*)d_out);
}

// Round 7
// 484.554 us; speedup vs baseline: 1.1255x; 1.1255x over previous
//
#include <hip/hip_runtime.h>

#define TLEN 300
#define THETA 10.0f
#define REF_DECAY 0.36787944117144233f

// FIR LDS row geometry: 101 quads (404 floats) per row. Data at quads 25..99
// (words 100..399), zero pads at quads 0..24 and quad 100.
#define QS 101
#define DQ 25

// ---------------- eps table: eps[k] = (k/10) * exp(1 - k/10), k=0..99; [100..103]=0 ----
__global__ void eps_init_kernel(float* __restrict__ eps) {
  int k = threadIdx.x;
  if (k < 104) eps[k] = 0.f;
  if (k < 100) {
    float a = (float)k / 10.0f;
    eps[k] = a * expf(1.0f - a);
  }
}

// 4-tap x 16-output FMA block. Window Wm,W0..W3 = x[base-4 .. base+15] where
// base = 16l - 4g. Per-output k-ascending order == prior verified rounds.
#define FIRSTEP16(e)                                                                     \
  acc[0] += e.x * W0.x;  acc[1] += e.x * W0.y;  acc[2] += e.x * W0.z;  acc[3] += e.x * W0.w; \
  acc[4] += e.x * W1.x;  acc[5] += e.x * W1.y;  acc[6] += e.x * W1.z;  acc[7] += e.x * W1.w; \
  acc[8] += e.x * W2.x;  acc[9] += e.x * W2.y;  acc[10] += e.x * W2.z; acc[11] += e.x * W2.w; \
  acc[12] += e.x * W3.x; acc[13] += e.x * W3.y; acc[14] += e.x * W3.z; acc[15] += e.x * W3.w; \
  acc[0] += e.y * Wm.w;  acc[1] += e.y * W0.x;  acc[2] += e.y * W0.y;  acc[3] += e.y * W0.z; \
  acc[4] += e.y * W0.w;  acc[5] += e.y * W1.x;  acc[6] += e.y * W1.y;  acc[7] += e.y * W1.z; \
  acc[8] += e.y * W1.w;  acc[9] += e.y * W2.x;  acc[10] += e.y * W2.y; acc[11] += e.y * W2.z; \
  acc[12] += e.y * W2.w; acc[13] += e.y * W3.x; acc[14] += e.y * W3.y; acc[15] += e.y * W3.z; \
  acc[0] += e.z * Wm.z;  acc[1] += e.z * Wm.w;  acc[2] += e.z * W0.x;  acc[3] += e.z * W0.y; \
  acc[4] += e.z * W0.z;  acc[5] += e.z * W0.w;  acc[6] += e.z * W1.x;  acc[7] += e.z * W1.y; \
  acc[8] += e.z * W1.z;  acc[9] += e.z * W1.w;  acc[10] += e.z * W2.x; acc[11] += e.z * W2.y; \
  acc[12] += e.z * W2.z; acc[13] += e.z * W2.w; acc[14] += e.z * W3.x; acc[15] += e.z * W3.y; \
  acc[0] += e.w * Wm.y;  acc[1] += e.w * Wm.z;  acc[2] += e.w * Wm.w;  acc[3] += e.w * W0.x; \
  acc[4] += e.w * W0.y;  acc[5] += e.w * W0.z;  acc[6] += e.w * W0.w;  acc[7] += e.w * W1.x; \
  acc[8] += e.w * W1.y;  acc[9] += e.w * W1.z;  acc[10] += e.w * W1.w; acc[11] += e.w * W2.x; \
  acc[12] += e.w * W2.y; acc[13] += e.w * W2.z; acc[14] += e.w * W2.w; acc[15] += e.w * W3.x;

// ---------------- 100-tap FIR: 16 outputs/thread, eps from global (L1), ----------------
// ~29 LDS b128/thread. acc[j] = sum_k eps[k]*x[16l+j-k], k ascending.
__device__ __forceinline__ void fir100w(const float4* __restrict__ row4, int l,
                                        const float* __restrict__ epsg, float acc[16]) {
  const int dq = DQ + 4 * l;
  float4 Wm = row4[dq - 1];
  float4 W0 = row4[dq];
  float4 W1 = row4[dq + 1];
  float4 W2 = row4[dq + 2];
  float4 W3 = row4[dq + 3];
#pragma unroll
  for (int j = 0; j < 16; ++j) acc[j] = 0.f;
#pragma unroll 1
  for (int g0 = 0; g0 < 20; g0 += 5) {
#pragma unroll
    for (int gg = 0; gg < 5; ++gg) {
      const int g = g0 + gg;
      const float4 e = *reinterpret_cast<const float4*>(epsg + 4 * g);
      FIRSTEP16(e);
      W3 = W2; W2 = W1; W1 = W0; W0 = Wm;
      Wm = row4[dq - 2 - g];
    }
    __builtin_amdgcn_sched_barrier(0);  // cap in-flight loads (VGPR control)
  }
#pragma unroll
  for (int gg = 0; gg < 5; ++gg) {
    const float4 e = *reinterpret_cast<const float4*>(epsg + 80 + 4 * gg);
    FIRSTEP16(e);
    W3 = W2; W2 = W1; W1 = W0; W0 = Wm;
    if (gg < 4) Wm = row4[dq - 22 - gg];
  }
}

// Write 16 outputs (4 quads) for task (r,l); quad 4l+jq valid iff < 75.
__device__ __forceinline__ void fir_store(const float acc[16], float* __restrict__ out,
                                          long row, int l) {
  float* op = out + row * TLEN + 16 * l;
#pragma unroll
  for (int jq = 0; jq < 4; ++jq) {
    if (4 * l + jq < 75)
      *reinterpret_cast<float4*>(op + 4 * jq) =
          make_float4(acc[4 * jq], acc[4 * jq + 1], acc[4 * jq + 2], acc[4 * jq + 3]);
  }
}

__device__ __forceinline__ void fir_zero_pads(float4* xs, int tid) {
  for (int i = tid; i < 416; i += 320) {
    int r = i / 26, k = i - r * 26;
    int q = (k < 25) ? k : 100;
    xs[r * QS + q] = make_float4(0.f, 0.f, 0.f, 0.f);
  }
}

// ---------------- phase-pure FIR: psp of 16 rows/block -> global ----------------
__global__ __launch_bounds__(320, 4) void fir_kernel(const float* __restrict__ in,
                                                     float* __restrict__ out,
                                                     const float* __restrict__ epsg) {
  __shared__ float4 xs[16 * QS];
  const int tid = threadIdx.x;
  const long row0 = (long)blockIdx.x * 16;
  fir_zero_pads(xs, tid);
  for (int i = tid; i < 1200; i += 320) {
    int r = i / 75, q = i - r * 75;
    xs[r * QS + DQ + q] = *reinterpret_cast<const float4*>(in + (row0 + r) * TLEN + 4 * q);
  }
  __syncthreads();
  if (tid < 304) {
    int r = tid & 15, l = tid >> 4;  // l in 0..18
    float acc[16];
    fir100w(xs + r * QS, l, epsg, acc);
    fir_store(acc, out, row0 + r, l);
  }
}

// ---------------- L1: pool4 fused into staging, then FIR ----------------
__global__ __launch_bounds__(320, 4) void pool4_fir_kernel(const float* __restrict__ in,
                                                           float* __restrict__ out,
                                                           const float* __restrict__ epsg) {
  __shared__ float4 xs[16 * QS];
  const int tid = threadIdx.x;
  const long row0 = (long)blockIdx.x * 16;
  fir_zero_pads(xs, tid);
  for (int i = tid; i < 1200; i += 320) {
    int r = i / 75, q = i - r * 75;
    long orow = row0 + r;
    int bc = (int)(orow >> 10);
    int y = (int)((orow >> 5) & 31);
    int x = (int)(orow & 31);
    const float* base = in + ((long)(bc * 128 + y * 4) * 128 + x * 4) * TLEN + 4 * q;
    float4 s = make_float4(0.f, 0.f, 0.f, 0.f);
#pragma unroll
    for (int dy = 0; dy < 4; ++dy)
#pragma unroll
      for (int dx = 0; dx < 4; ++dx) {
        float4 v = *reinterpret_cast<const float4*>(base + (dy * 128 + dx) * TLEN);
        s.x += v.x; s.y += v.y; s.z += v.z; s.w += v.w;
      }
    s.x *= 0.6875f; s.y *= 0.6875f; s.z *= 0.6875f; s.w *= 0.6875f;
    xs[r * QS + DQ + q] = s;
  }
  __syncthreads();
  if (tid < 304) {
    int r = tid & 15, l = tid >> 4;
    float acc[16];
    fir100w(xs + r * QS, l, epsg, acc);
    fir_store(acc, out, row0 + r, l);
  }
}

// ---------------- FIR with fused per-channel delay gather on input (L7) ----------------
__global__ __launch_bounds__(320, 4) void fir_delay_kernel(const float* __restrict__ in,
                                                           float* __restrict__ out,
                                                           const float* __restrict__ epsg,
                                                           const float* __restrict__ dly) {
  __shared__ float4 xs[16 * QS];
  const int tid = threadIdx.x;
  const long row0 = (long)blockIdx.x * 16;
  fir_zero_pads(xs, tid);
  for (int i = tid; i < 1200; i += 320) {
    int r = i / 75, q = i - r * 75;
    long row = row0 + r;
    float dd = dly[(int)(row & 511)];  // C = 512
    const float* rowp = in + row * TLEN;
    float4 o;
    float* op = &o.x;
#pragma unroll
    for (int j = 0; j < 4; ++j) {
      int t = 4 * q + j;
      float src = (float)t - dd;
      float fi = floorf(src);
      int i0 = (int)fi;  // in [-4, 299]
      float wf = src - fi;
      float v0 = (i0 >= 0 && i0 < TLEN) ? rowp[min(max(i0, 0), TLEN - 1)] : 0.f;
      float v1 = (i0 + 1 >= 0 && i0 + 1 < TLEN) ? rowp[min(max(i0 + 1, 0), TLEN - 1)] : 0.f;
      op[j] = v0 * (1.f - wf) + v1 * wf;
    }
    xs[r * QS + DQ + q] = o;
  }
  __syncthreads();
  if (tid < 304) {
    int r = tid & 15, l = tid >> 4;
    float acc[16];
    fir100w(xs + r * QS, l, epsg, acc);
    fir_store(acc, out, row0 + r, l);
  }
}

// ---------------- in-place refractory scan: 1 row/lane, direct global, 4-deep prefetch ----
__global__ __launch_bounds__(64) void scan_kernel(float* __restrict__ u, long rows) {
  long row = (long)blockIdx.x * 64 + threadIdx.x;
  if (row >= rows) return;
  float* p = u + row * TLEN;
  float4 q0 = *reinterpret_cast<const float4*>(p);
  float4 q1 = *reinterpret_cast<const float4*>(p + 4);
  float4 q2 = *reinterpret_cast<const float4*>(p + 8);
  float4 q3 = *reinterpret_cast<const float4*>(p + 12);
  float ref = 0.f;
#pragma unroll 4
  for (int c4 = 0; c4 < 75; ++c4) {
    float4 u4 = q0;
    q0 = q1; q1 = q2; q2 = q3;
    if (c4 < 71) q3 = *reinterpret_cast<const float4*>(p + 4 * (c4 + 4));
    float v, sp;
    v = u4.x + ref - THETA; sp = (v >= 0.f) ? 1.f : 0.f; u4.x = sp; ref = REF_DECAY * ref - 20.0f * sp;
    v = u4.y + ref - THETA; sp = (v >= 0.f) ? 1.f : 0.f; u4.y = sp; ref = REF_DECAY * ref - 20.0f * sp;
    v = u4.z + ref - THETA; sp = (v >= 0.f) ? 1.f : 0.f; u4.z = sp; ref = REF_DECAY * ref - 20.0f * sp;
    v = u4.w + ref - THETA; sp = (v >= 0.f) ? 1.f : 0.f; u4.w = sp; ref = REF_DECAY * ref - 20.0f * sp;
    *reinterpret_cast<float4*>(p + 4 * c4) = u4;
  }
}

// ---------------- fc1 4-partial sum + scan -> spikes S5 ----------------
__global__ __launch_bounds__(64) void scan_reduce4_kernel(const float* __restrict__ part,
                                                          float* __restrict__ s) {
  long row = (long)blockIdx.x * 64 + threadIdx.x;  // 2048 rows
  const float* p = part + row * TLEN;
  float* o = s + row * TLEN;
  float ref = 0.f;
#pragma unroll 4
  for (int c4 = 0; c4 < 75; ++c4) {
    const float4 v0 = *reinterpret_cast<const float4*>(p + 4 * c4);
    const float4 v1 = *reinterpret_cast<const float4*>(p + 614400 + 4 * c4);
    const float4 v2 = *reinterpret_cast<const float4*>(p + 1228800 + 4 * c4);
    const float4 v3 = *reinterpret_cast<const float4*>(p + 1843200 + 4 * c4);
    float4 u4;
    u4.x = (v0.x + v1.x) + (v2.x + v3.x);
    u4.y = (v0.y + v1.y) + (v2.y + v3.y);
    u4.z = (v0.z + v1.z) + (v2.z + v3.z);
    u4.w = (v0.w + v1.w) + (v2.w + v3.w);
    float v, sp;
    v = u4.x + ref - THETA; sp = (v >= 0.f) ? 1.f : 0.f; u4.x = sp; ref = REF_DECAY * ref - 20.0f * sp;
    v = u4.y + ref - THETA; sp = (v >= 0.f) ? 1.f : 0.f; u4.y = sp; ref = REF_DECAY * ref - 20.0f * sp;
    v = u4.z + ref - THETA; sp = (v >= 0.f) ? 1.f : 0.f; u4.z = sp; ref = REF_DECAY * ref - 20.0f * sp;
    v = u4.w + ref - THETA; sp = (v >= 0.f) ? 1.f : 0.f; u4.w = sp; ref = REF_DECAY * ref - 20.0f * sp;
    *reinterpret_cast<float4*>(o + 4 * c4) = u4;
  }
}

// ---------------- fused spike scan + 2x2 pool + per-channel delay (round-5 proven) -------
__device__ __forceinline__ int sqz(int r, int q) { return (q & ~7) | ((q + r) & 7); }

__global__ __launch_bounds__(256) void spike_pool2_delay_kernel(const float* __restrict__ u,
                                                                const float* __restrict__ dly,
                                                                float* __restrict__ out,
                                                                int WI, int C) {
  __shared__ float4 ch[64 * 16];            // chunk: 64 rows x 15 quads (60 t), swizzled
  __shared__ unsigned int bits[64 * 13];    // spike bits, stride 13 (odd)
  const int tid = threadIdx.x;
  const long inrow0 = (long)blockIdx.x * 64;
  float ref = 0.f;
  unsigned int wbits = 0;
  for (int cix = 0; cix < 5; ++cix) {
    __syncthreads();
    for (int i = tid; i < 960; i += 256) {
      int r = i / 15, q = i - r * 15;
      ch[r * 16 + sqz(r, q)] = *reinterpret_cast<const float4*>(
          u + (inrow0 + r) * TLEN + cix * 60 + 4 * q);
    }
    __syncthreads();
    if (tid < 64) {
      int r = tid;
#pragma unroll 1
      for (int q = 0; q < 15; ++q) {
        float4 v = ch[r * 16 + sqz(r, q)];
        int t = cix * 60 + 4 * q;
        float x, sp;
        x = v.x + ref - THETA; sp = (x >= 0.f) ? 1.f : 0.f; ref = REF_DECAY * ref - 20.0f * sp;
        wbits |= ((unsigned int)sp) << (t & 31);
        if ((t & 31) == 31) { bits[r * 13 + (t >> 5)] = wbits; wbits = 0; }
        x = v.y + ref - THETA; sp = (x >= 0.f) ? 1.f : 0.f; ref = REF_DECAY * ref - 20.0f * sp;
        wbits |= ((unsigned int)sp) << ((t + 1) & 31);
        if (((t + 1) & 31) == 31) { bits[r * 13 + ((t + 1) >> 5)] = wbits; wbits = 0; }
        x = v.z + ref - THETA; sp = (x >= 0.f) ? 1.f : 0.f; ref = REF_DECAY * ref - 20.0f * sp;
        wbits |= ((unsigned int)sp) << ((t + 2) & 31);
        if (((t + 2) & 31) == 31) { bits[r * 13 + ((t + 2) >> 5)] = wbits; wbits = 0; }
        x = v.w + ref - THETA; sp = (x >= 0.f) ? 1.f : 0.f; ref = REF_DECAY * ref - 20.0f * sp;
        wbits |= ((unsigned int)sp) << ((t + 3) & 31);
        if (((t + 3) & 31) == 31) { bits[r * 13 + ((t + 3) >> 5)] = wbits; wbits = 0; }
      }
    }
  }
  if (tid < 64) bits[tid * 13 + 9] = wbits;  // final partial word (t=288..299)
  __syncthreads();
  const int WO = WI >> 1;
  const int bc = (int)(inrow0 / (WI * WI));
  const int y0 = (int)((inrow0 % (WI * WI)) / WI);
  const float dd = dly[bc % C];
  const long orow0 = (long)bc * (WO * WO) + (y0 >> 1) * WO;
  for (int i = tid; i < 4800; i += 256) {
    int ro = i / TLEN, t = i - ro * TLEN;
    int Yr = ro / WO, X = ro - Yr * WO;
    int ir = (2 * Yr) * WI + 2 * X;
    float src = (float)t - dd;
    float fi = floorf(src);
    int i0 = (int)fi;
    float wf = src - fi;
    bool ok0 = (i0 >= 0) && (i0 < TLEN);
    bool ok1 = (i0 + 1 >= 0) && (i0 + 1 < TLEN);
    int j0 = min(max(i0, 0), TLEN - 1);
    int j1 = min(max(i0 + 1, 0), TLEN - 1);
    int s0i = 0, s1i = 0;
#pragma unroll
    for (int dy = 0; dy < 2; ++dy)
#pragma unroll
      for (int dx = 0; dx < 2; ++dx) {
        int rr = ir + dy * WI + dx;
        s0i += (int)((bits[rr * 13 + (j0 >> 5)] >> (j0 & 31)) & 1u);
        s1i += (int)((bits[rr * 13 + (j1 >> 5)] >> (j1 & 31)) & 1u);
      }
    float s0 = ok0 ? (float)s0i : 0.f;
    float s1 = ok1 ? (float)s1i : 0.f;
    out[(orow0 + ro) * TLEN + t] = (s0 * (1.f - wf) + s1 * wf) * 2.75f;
  }
}

// ---------------- conv1: 2->16 ch, 5x5, pad 2, 32x32, float4 staging ----------------
__global__ __launch_bounds__(256) void conv1_kernel(const float* __restrict__ in,
                                                    const float* __restrict__ w,
                                                    float* __restrict__ out) {
  __shared__ float xl[11520];  // [c2][dy5][x36][t32]
  const int tid = threadIdx.x;
  const int t0 = blockIdx.x * 32;
  const int y = blockIdx.y;
  const int b = blockIdx.z;
  for (int i = tid; i < 2880; i += 256) {
    int tq = i & 7;
    int rest = i >> 3;
    int xp = rest % 36;
    int r2 = rest / 36;
    int dy = r2 % 5;
    int c = r2 / 5;
    int yy = y + dy - 2, xx = xp - 2, t = t0 + tq * 4;
    float4 v = {0.f, 0.f, 0.f, 0.f};
    if (yy >= 0 && yy < 32 && xx >= 0 && xx < 32 && t < TLEN)
      v = *reinterpret_cast<const float4*>(
          in + ((long)((b * 2 + c) * 32 + yy) * 32 + xx) * TLEN + t);
    *reinterpret_cast<float4*>(&xl[rest * 32 + tq * 4]) = v;
  }
  __syncthreads();
  const int tg = tid & 7;
  const int x = tid >> 3;
  float acc[16][4];
#pragma unroll
  for (int o = 0; o < 16; ++o) { acc[o][0] = acc[o][1] = acc[o][2] = acc[o][3] = 0.f; }
  for (int c = 0; c < 2; ++c)
#pragma unroll
    for (int dy = 0; dy < 5; ++dy)
#pragma unroll
      for (int kx = 0; kx < 5; ++kx) {
        const float4 xv = *reinterpret_cast<const float4*>(
            &xl[((c * 5 + dy) * 36 + x + kx) * 32 + tg * 4]);
        const float* wp = w + (c * 5 + dy) * 5 + kx;
#pragma unroll
        for (int o = 0; o < 16; ++o) {
          float wsc = wp[o * 50];
          acc[o][0] += wsc * xv.x; acc[o][1] += wsc * xv.y;
          acc[o][2] += wsc * xv.z; acc[o][3] += wsc * xv.w;
        }
      }
  const int t = t0 + tg * 4;
  if (t < TLEN) {
#pragma unroll
    for (int o = 0; o < 16; ++o) {
      float4 res; res.x = acc[o][0]; res.y = acc[o][1]; res.z = acc[o][2]; res.w = acc[o][3];
      *reinterpret_cast<float4*>(&out[((long)((b * 16 + o) * 32 + y) * 32 + x) * TLEN + t]) = res;
    }
  }
}

// ---------------- conv2: 16->32 ch, 3x3, pad 1, 16x16, float4 staging ----------------
__global__ __launch_bounds__(256) void conv2_kernel(const float* __restrict__ in,
                                                    const float* __restrict__ w,
                                                    float* __restrict__ out) {
  __shared__ float xl[13824];  // [c16][dy3][x18][t16]
  const int tid = threadIdx.x;
  const int t0 = blockIdx.x * 16;
  const int y = blockIdx.y;
  const int b = blockIdx.z;
  for (int i = tid; i < 3456; i += 256) {
    int tq = i & 3;
    int rest = i >> 2;
    int xp = rest % 18;
    int r2 = rest / 18;
    int dy = r2 % 3;
    int c = r2 / 3;
    int yy = y + dy - 1, xx = xp - 1, t = t0 + tq * 4;
    float4 v = {0.f, 0.f, 0.f, 0.f};
    if (yy >= 0 && yy < 16 && xx >= 0 && xx < 16 && t < TLEN)
      v = *reinterpret_cast<const float4*>(
          in + ((long)((b * 16 + c) * 16 + yy) * 16 + xx) * TLEN + t);
    *reinterpret_cast<float4*>(&xl[rest * 16 + tq * 4]) = v;
  }
  __syncthreads();
  const int tg = tid & 3;
  const int x = (tid >> 2) & 15;
  const int oh = tid >> 6;
  float acc[8][4];
#pragma unroll
  for (int o = 0; o < 8; ++o) { acc[o][0] = acc[o][1] = acc[o][2] = acc[o][3] = 0.f; }
  for (int c = 0; c < 16; ++c)
#pragma unroll
    for (int dy = 0; dy < 3; ++dy)
#pragma unroll
      for (int kx = 0; kx < 3; ++kx) {
        const float4 xv = *reinterpret_cast<const float4*>(
            &xl[((c * 3 + dy) * 18 + x + kx) * 16 + tg * 4]);
        const float* wp = w + (c * 3 + dy) * 3 + kx;
#pragma unroll
        for (int oo = 0; oo < 8; ++oo) {
          float wsc = wp[(oh * 8 + oo) * 144];
          acc[oo][0] += wsc * xv.x; acc[oo][1] += wsc * xv.y;
          acc[oo][2] += wsc * xv.z; acc[oo][3] += wsc * xv.w;
        }
      }
  const int t = t0 + tg * 4;
  if (t < TLEN) {
#pragma unroll
    for (int oo = 0; oo < 8; ++oo) {
      int o = oh * 8 + oo;
      float4 res; res.x = acc[oo][0]; res.y = acc[oo][1]; res.z = acc[oo][2]; res.w = acc[oo][3];
      *reinterpret_cast<float4*>(&out[((long)((b * 32 + o) * 16 + y) * 16 + x) * TLEN + t]) = res;
    }
  }
}

// ---------------- fc1: k-split x4, 64x64 tiles, float4 staging, partials out ----------------
__global__ __launch_bounds__(256) void fc1_kernel(const float* __restrict__ x,
                                                  const float* __restrict__ w,
                                                  float* __restrict__ part) {
  __shared__ float wl[64][44];
  __shared__ float xlb[32][68];
  const int tid = threadIdx.x;
  const int t0 = blockIdx.x * 64;
  const int o0 = blockIdx.y * 64;
  const int b = blockIdx.z >> 2;
  const int split = blockIdx.z & 3;
  const int tx = tid & 15, ty = tid >> 4;
  float acc[4][4];
#pragma unroll
  for (int i = 0; i < 4; ++i)
#pragma unroll
    for (int j = 0; j < 4; ++j) acc[i][j] = 0.f;
  const int kbeg = split * 512;
  for (int kc = kbeg; kc < kbeg + 512; kc += 32) {
    __syncthreads();
#pragma unroll
    for (int rr = 0; rr < 2; ++rr) {
      int i = rr * 256 + tid;
      int ol = i >> 3, kq = i & 7;
      float4 v = *reinterpret_cast<const float4*>(w + (long)(o0 + ol) * 2048 + kc + kq * 4);
      *reinterpret_cast<float4*>(&wl[ol][kq * 4]) = v;
    }
#pragma unroll
    for (int rr = 0; rr < 2; ++rr) {
      int i = rr * 256 + tid;
      int kl = i >> 4, tq = i & 15;
      int t = t0 + tq * 4;
      float4 v = {0.f, 0.f, 0.f, 0.f};
      if (t < TLEN)
        v = *reinterpret_cast<const float4*>(x + ((long)b * 2048 + kc + kl) * TLEN + t);
      *reinterpret_cast<float4*>(&xlb[kl][tq * 4]) = v;
    }
    __syncthreads();
#pragma unroll
    for (int k4 = 0; k4 < 8; ++k4) {
      float4 wq[4], xq[4];
#pragma unroll
      for (int i = 0; i < 4; ++i)
        wq[i] = *reinterpret_cast<const float4*>(&wl[ty * 4 + i][k4 * 4]);
#pragma unroll
      for (int j = 0; j < 4; ++j)
        xq[j] = *reinterpret_cast<const float4*>(&xlb[k4 * 4 + j][tx * 4]);
#pragma unroll
      for (int i = 0; i < 4; ++i) {
        float wa[4] = {wq[i].x, wq[i].y, wq[i].z, wq[i].w};
#pragma unroll
        for (int j = 0; j < 4; ++j) {
          float xa[4] = {xq[j].x, xq[j].y, xq[j].z, xq[j].w};
          acc[i][0] += wa[j] * xa[0]; acc[i][1] += wa[j] * xa[1];
          acc[i][2] += wa[j] * xa[2]; acc[i][3] += wa[j] * xa[3];
        }
      }
    }
  }
  const int t = t0 + tx * 4;
  if (t < TLEN) {
#pragma unroll
    for (int i = 0; i < 4; ++i) {
      float4 res; res.x = acc[i][0]; res.y = acc[i][1]; res.z = acc[i][2]; res.w = acc[i][3];
      *reinterpret_cast<float4*>(
          part + ((long)(split * 4 + b) * 512 + o0 + ty * 4 + i) * TLEN + t) = res;
    }
  }
}

// ---------------- fc2 + final spike scan fused, writes d_out ----------------
__global__ __launch_bounds__(320) void fc2_spike_kernel(const float* __restrict__ x,
                                                        const float* __restrict__ w,
                                                        float* __restrict__ out) {
  __shared__ float ul[304];
  int blk = blockIdx.x;
  int b = blk / 11, o = blk % 11;
  int t = threadIdx.x;
  if (t < TLEN) {
    const float* xr = x + (long)b * 512 * TLEN + t;
    const float* wr = w + o * 512;
    float a0 = 0.f, a1 = 0.f, a2 = 0.f, a3 = 0.f;
#pragma unroll 4
    for (int i = 0; i < 512; i += 4) {
      a0 += wr[i] * xr[(long)i * TLEN];
      a1 += wr[i + 1] * xr[(long)(i + 1) * TLEN];
      a2 += wr[i + 2] * xr[(long)(i + 2) * TLEN];
      a3 += wr[i + 3] * xr[(long)(i + 3) * TLEN];
    }
    ul[t] = (a0 + a1) + (a2 + a3);
  }
  __syncthreads();
  if (t == 0) {
    float ref = 0.f;
#pragma unroll 4
    for (int c = 0; c < TLEN; ++c) {
      float v = ul[c] + ref - THETA;
      float sp = (v >= 0.f) ? 1.f : 0.f;
      ul[c] = sp;
      ref = REF_DECAY * ref - 20.0f * sp;
    }
  }
  __syncthreads();
  if (t < TLEN) out[((long)b * 11 + o) * TLEN + t] = ul[t];
}

extern "C" void kernel_launch(void* const* d_in, const int* in_sizes, int n_in,
                              void* d_out, int out_size, void* d_ws, size_t ws_size,
                              hipStream_t stream) {
  const float* input = (const float*)d_in[0];
  const float* w1    = (const float*)d_in[1];
  const float* w2    = (const float*)d_in[2];
  const float* wfc1  = (const float*)d_in[3];
  const float* wfc2  = (const float*)d_in[4];
  const float* d1    = (const float*)d_in[5];
  const float* d2    = (const float*)d_in[6];
  const float* d3    = (const float*)d_in[7];

  float* ws   = (float*)d_ws;
  float* big0 = ws;                    // conv u (19.66M) / fc1 partials (2.46M)
  float* medA = big0 + 19660800;
  float* medB = medA + 4915200;
  float* fcA  = medB + 4915200;
  float* fcB  = fcA + 614400;
  float* eps  = fcB + 614400;

  hipLaunchKernelGGL(eps_init_kernel, dim3(1), dim3(128), 0, stream, eps);

  // L1: pool4+psp -> u (medB); scan in-place -> S0; psp -> medA = psp(S0)
  hipLaunchKernelGGL(pool4_fir_kernel, dim3(512), dim3(320), 0, stream, input, medB, eps);
  hipLaunchKernelGGL(scan_kernel, dim3(128), dim3(64), 0, stream, medB, 8192L);
  hipLaunchKernelGGL(fir_kernel, dim3(512), dim3(320), 0, stream, medB, medA, eps);
  // L2: conv1 -> u1 (big0); fused spike+pool2+delay1 -> medB
  hipLaunchKernelGGL(conv1_kernel, dim3(10, 32, 4), dim3(256), 0, stream, medA, w1, big0);
  hipLaunchKernelGGL(spike_pool2_delay_kernel, dim3(1024), dim3(256), 0, stream,
                     big0, d1, medB, 32, 16);
  // L3: psp -> u (medA); scan -> S2; psp -> medB = psp(S2)
  hipLaunchKernelGGL(fir_kernel, dim3(1024), dim3(320), 0, stream, medB, medA, eps);
  hipLaunchKernelGGL(scan_kernel, dim3(256), dim3(64), 0, stream, medA, 16384L);
  hipLaunchKernelGGL(fir_kernel, dim3(1024), dim3(320), 0, stream, medA, medB, eps);
  // L4: conv2 -> u3 (big0); fused spike+pool2+delay2 -> medA
  hipLaunchKernelGGL(conv2_kernel, dim3(19, 16, 4), dim3(256), 0, stream, medB, w2, big0);
  hipLaunchKernelGGL(spike_pool2_delay_kernel, dim3(512), dim3(256), 0, stream,
                     big0, d2, medA, 16, 32);
  // L5: psp -> u (medB); scan -> S4; psp -> medA = psp(S4)
  hipLaunchKernelGGL(fir_kernel, dim3(512), dim3(320), 0, stream, medA, medB, eps);
  hipLaunchKernelGGL(scan_kernel, dim3(128), dim3(64), 0, stream, medB, 8192L);
  hipLaunchKernelGGL(fir_kernel, dim3(512), dim3(320), 0, stream, medB, medA, eps);
  // L6: fc1 -> partials (big0); sum+scan -> S5 (fcA)
  hipLaunchKernelGGL(fc1_kernel, dim3(5, 8, 16), dim3(256), 0, stream, medA, wfc1, big0);
  hipLaunchKernelGGL(scan_reduce4_kernel, dim3(32), dim3(64), 0, stream, big0, fcA);
  // L7: delay3+psp -> fcB; fc2+spike -> d_out
  hipLaunchKernelGGL(fir_delay_kernel, dim3(128), dim3(320), 0, stream, fcA, fcB, eps, d3);
  hipLaunchKernelGGL(fc2_spike_kernel, dim3(44), dim3(320), 0, stream, fcB, wfc2, (float*)d_out);
}

// Round 8
// 479.048 us; speedup vs baseline: 1.1384x; 1.0115x over previous
//
#include <hip/hip_runtime.h>

#define TLEN 300
#define THETA 10.0f
#define REF_DECAY 0.36787944117144233f

// ---------------- eps table: eps[k] = (k/10) * exp(1 - k/10), k=0..99; [100..103]=0 ----
__global__ void eps_init_kernel(float* __restrict__ eps) {
  int k = threadIdx.x;
  if (k < 104) eps[k] = 0.f;
  if (k < 100) {
    float a = (float)k / 10.0f;
    eps[k] = a * expf(1.0f - a);
  }
}

// 4-tap x 8-output FMA block; statement order identical to prior verified rounds.
#define FIRSTEP(e, A, B, C)                                                              \
  acc[0] += e.x * B.x; acc[1] += e.x * B.y; acc[2] += e.x * B.z; acc[3] += e.x * B.w;    \
  acc[4] += e.x * C.x; acc[5] += e.x * C.y; acc[6] += e.x * C.z; acc[7] += e.x * C.w;    \
  acc[0] += e.y * A.w; acc[1] += e.y * B.x; acc[2] += e.y * B.y; acc[3] += e.y * B.z;    \
  acc[4] += e.y * B.w; acc[5] += e.y * C.x; acc[6] += e.y * C.y; acc[7] += e.y * C.z;    \
  acc[0] += e.z * A.z; acc[1] += e.z * A.w; acc[2] += e.z * B.x; acc[3] += e.z * B.y;    \
  acc[4] += e.z * B.z; acc[5] += e.z * B.w; acc[6] += e.z * C.x; acc[7] += e.z * C.y;    \
  acc[0] += e.w * A.y; acc[1] += e.w * A.z; acc[2] += e.w * A.w; acc[3] += e.w * B.x;    \
  acc[4] += e.w * B.y; acc[5] += e.w * B.z; acc[6] += e.w * B.w; acc[7] += e.w * C.x;

// load quad at word offset w of a row (w multiple of 4); zero if OOB.
__device__ __forceinline__ float4 ldq(const float* __restrict__ rowp, int w) {
  if (w >= 0 && w < TLEN) return *reinterpret_cast<const float4*>(rowp + w);
  return make_float4(0.f, 0.f, 0.f, 0.f);
}

// ---------------- direct-from-global 100-tap FIR: 8 outputs/thread, no LDS/barriers ----
// task = row * 38 + l; outputs t = 8l..8l+7. acc[j] = sum_k eps[k]*x[8l+j-k], k ascending.
__global__ __launch_bounds__(256) void fir_direct_kernel(const float* __restrict__ in,
                                                         float* __restrict__ out,
                                                         const float* __restrict__ epsg,
                                                         int rows) {
  int task = blockIdx.x * 256 + threadIdx.x;
  int row = task / 38;
  int l = task - row * 38;
  if (row >= rows) return;
  const float* rowp = in + (long)row * TLEN;
  const int t0 = 8 * l;
  float4 A = ldq(rowp, t0 - 4);
  float4 B = ldq(rowp, t0);
  float4 C = ldq(rowp, t0 + 4);
  float acc[8];
#pragma unroll
  for (int j = 0; j < 8; ++j) acc[j] = 0.f;
#pragma unroll 1
  for (int kg0 = 0; kg0 < 80; kg0 += 20) {
    const float* ep = epsg + kg0;
#pragma unroll
    for (int kk = 0; kk < 5; ++kk) {
      const float4 e = *reinterpret_cast<const float4*>(ep + 4 * kk);
      const int kg = kg0 + 4 * kk;
      FIRSTEP(e, A, B, C);
      C = B; B = A;
      A = ldq(rowp, t0 - kg - 8);
    }
    __builtin_amdgcn_sched_barrier(0);  // cap in-flight loads (VGPR control)
  }
#pragma unroll
  for (int kk = 0; kk < 5; ++kk) {
    const float4 e = *reinterpret_cast<const float4*>(epsg + 80 + 4 * kk);
    FIRSTEP(e, A, B, C);
    C = B; B = A;
    if (kk < 4) A = ldq(rowp, t0 - 88 - 4 * kk);
  }
  float* op = out + (long)row * TLEN + t0;
  *reinterpret_cast<float4*>(op) = make_float4(acc[0], acc[1], acc[2], acc[3]);
  if (t0 + 4 < TLEN)
    *reinterpret_cast<float4*>(op + 4) = make_float4(acc[4], acc[5], acc[6], acc[7]);
}

// ---------------- in-place refractory scan: 1 row/lane, direct global, 4-deep prefetch ----
__global__ __launch_bounds__(64) void scan_kernel(float* __restrict__ u, long rows) {
  long row = (long)blockIdx.x * 64 + threadIdx.x;
  if (row >= rows) return;
  float* p = u + row * TLEN;
  float4 q0 = *reinterpret_cast<const float4*>(p);
  float4 q1 = *reinterpret_cast<const float4*>(p + 4);
  float4 q2 = *reinterpret_cast<const float4*>(p + 8);
  float4 q3 = *reinterpret_cast<const float4*>(p + 12);
  float ref = 0.f;
#pragma unroll 4
  for (int c4 = 0; c4 < 75; ++c4) {
    float4 u4 = q0;
    q0 = q1; q1 = q2; q2 = q3;
    if (c4 < 71) q3 = *reinterpret_cast<const float4*>(p + 4 * (c4 + 4));
    float v, sp;
    v = u4.x + ref - THETA; sp = (v >= 0.f) ? 1.f : 0.f; u4.x = sp; ref = REF_DECAY * ref - 20.0f * sp;
    v = u4.y + ref - THETA; sp = (v >= 0.f) ? 1.f : 0.f; u4.y = sp; ref = REF_DECAY * ref - 20.0f * sp;
    v = u4.z + ref - THETA; sp = (v >= 0.f) ? 1.f : 0.f; u4.z = sp; ref = REF_DECAY * ref - 20.0f * sp;
    v = u4.w + ref - THETA; sp = (v >= 0.f) ? 1.f : 0.f; u4.w = sp; ref = REF_DECAY * ref - 20.0f * sp;
    *reinterpret_cast<float4*>(p + 4 * c4) = u4;
  }
}

// ---------------- fc1 4-partial sum + scan -> spikes S5 ----------------
__global__ __launch_bounds__(64) void scan_reduce4_kernel(const float* __restrict__ part,
                                                          float* __restrict__ s) {
  long row = (long)blockIdx.x * 64 + threadIdx.x;  // 2048 rows
  const float* p = part + row * TLEN;
  float* o = s + row * TLEN;
  float ref = 0.f;
#pragma unroll 4
  for (int c4 = 0; c4 < 75; ++c4) {
    const float4 v0 = *reinterpret_cast<const float4*>(p + 4 * c4);
    const float4 v1 = *reinterpret_cast<const float4*>(p + 614400 + 4 * c4);
    const float4 v2 = *reinterpret_cast<const float4*>(p + 1228800 + 4 * c4);
    const float4 v3 = *reinterpret_cast<const float4*>(p + 1843200 + 4 * c4);
    float4 u4;
    u4.x = (v0.x + v1.x) + (v2.x + v3.x);
    u4.y = (v0.y + v1.y) + (v2.y + v3.y);
    u4.z = (v0.z + v1.z) + (v2.z + v3.z);
    u4.w = (v0.w + v1.w) + (v2.w + v3.w);
    float v, sp;
    v = u4.x + ref - THETA; sp = (v >= 0.f) ? 1.f : 0.f; u4.x = sp; ref = REF_DECAY * ref - 20.0f * sp;
    v = u4.y + ref - THETA; sp = (v >= 0.f) ? 1.f : 0.f; u4.y = sp; ref = REF_DECAY * ref - 20.0f * sp;
    v = u4.z + ref - THETA; sp = (v >= 0.f) ? 1.f : 0.f; u4.z = sp; ref = REF_DECAY * ref - 20.0f * sp;
    v = u4.w + ref - THETA; sp = (v >= 0.f) ? 1.f : 0.f; u4.w = sp; ref = REF_DECAY * ref - 20.0f * sp;
    *reinterpret_cast<float4*>(o + 4 * c4) = u4;
  }
}

// ---------------- 4x4 sum-pool on raw input (float4 over t), scale 0.6875 ----------------
__global__ __launch_bounds__(256) void pool4_kernel(const float* __restrict__ in,
                                                    float* __restrict__ out) {
  int idx = blockIdx.x * 256 + threadIdx.x;  // quad index
  if (idx >= 153600) return;
  int tq = idx % 75;
  int rest = idx / 75;
  int x = rest & 31; rest >>= 5;
  int y = rest & 31; rest >>= 5;  // rest = bc (0..7)
  const float* base = in + ((long)(rest * 128 + y * 4) * 128 + x * 4) * TLEN + tq * 4;
  float4 s = {0.f, 0.f, 0.f, 0.f};
#pragma unroll
  for (int dy = 0; dy < 4; ++dy)
#pragma unroll
    for (int dx = 0; dx < 4; ++dx) {
      float4 v = *reinterpret_cast<const float4*>(base + (dy * 128 + dx) * TLEN);
      s.x += v.x; s.y += v.y; s.z += v.z; s.w += v.w;
    }
  s.x *= 0.6875f; s.y *= 0.6875f; s.z *= 0.6875f; s.w *= 0.6875f;
  *reinterpret_cast<float4*>(out + ((long)(rest * 32 + y) * 32 + x) * TLEN + tq * 4) = s;
}

// ---------------- per-channel delay (lerp gather), C=512, S=1 ----------------
__global__ __launch_bounds__(256) void delay_kernel(const float* __restrict__ in,
                                                    const float* __restrict__ d,
                                                    float* __restrict__ out, int total) {
  int idx = blockIdx.x * 256 + threadIdx.x;
  if (idx >= total) return;
  int t = idx % TLEN;
  int rest = idx / TLEN;  // row = b*512 + c
  float dd = d[rest & 511];
  float src = (float)t - dd;
  float fi = floorf(src);
  int i0 = (int)fi;
  float wf = src - fi;
  const float* base = in + (long)rest * TLEN;
  float v0 = (i0 >= 0 && i0 < TLEN) ? base[min(max(i0, 0), TLEN - 1)] : 0.f;
  float v1 = (i0 + 1 >= 0 && i0 + 1 < TLEN) ? base[min(max(i0 + 1, 0), TLEN - 1)] : 0.f;
  out[idx] = v0 * (1.f - wf) + v1 * wf;
}

// ---------------- fused spike scan + 2x2 pool + per-channel delay (round-5 proven) -------
__device__ __forceinline__ int sqz(int r, int q) { return (q & ~7) | ((q + r) & 7); }

__global__ __launch_bounds__(256) void spike_pool2_delay_kernel(const float* __restrict__ u,
                                                                const float* __restrict__ dly,
                                                                float* __restrict__ out,
                                                                int WI, int C) {
  __shared__ float4 ch[64 * 16];            // chunk: 64 rows x 15 quads (60 t), swizzled
  __shared__ unsigned int bits[64 * 13];    // spike bits, stride 13 (odd)
  const int tid = threadIdx.x;
  const long inrow0 = (long)blockIdx.x * 64;
  float ref = 0.f;
  unsigned int wbits = 0;
  for (int cix = 0; cix < 5; ++cix) {
    __syncthreads();
    for (int i = tid; i < 960; i += 256) {
      int r = i / 15, q = i - r * 15;
      ch[r * 16 + sqz(r, q)] = *reinterpret_cast<const float4*>(
          u + (inrow0 + r) * TLEN + cix * 60 + 4 * q);
    }
    __syncthreads();
    if (tid < 64) {
      int r = tid;
#pragma unroll 1
      for (int q = 0; q < 15; ++q) {
        float4 v = ch[r * 16 + sqz(r, q)];
        int t = cix * 60 + 4 * q;
        float x, sp;
        x = v.x + ref - THETA; sp = (x >= 0.f) ? 1.f : 0.f; ref = REF_DECAY * ref - 20.0f * sp;
        wbits |= ((unsigned int)sp) << (t & 31);
        if ((t & 31) == 31) { bits[r * 13 + (t >> 5)] = wbits; wbits = 0; }
        x = v.y + ref - THETA; sp = (x >= 0.f) ? 1.f : 0.f; ref = REF_DECAY * ref - 20.0f * sp;
        wbits |= ((unsigned int)sp) << ((t + 1) & 31);
        if (((t + 1) & 31) == 31) { bits[r * 13 + ((t + 1) >> 5)] = wbits; wbits = 0; }
        x = v.z + ref - THETA; sp = (x >= 0.f) ? 1.f : 0.f; ref = REF_DECAY * ref - 20.0f * sp;
        wbits |= ((unsigned int)sp) << ((t + 2) & 31);
        if (((t + 2) & 31) == 31) { bits[r * 13 + ((t + 2) >> 5)] = wbits; wbits = 0; }
        x = v.w + ref - THETA; sp = (x >= 0.f) ? 1.f : 0.f; ref = REF_DECAY * ref - 20.0f * sp;
        wbits |= ((unsigned int)sp) << ((t + 3) & 31);
        if (((t + 3) & 31) == 31) { bits[r * 13 + ((t + 3) >> 5)] = wbits; wbits = 0; }
      }
    }
  }
  if (tid < 64) bits[tid * 13 + 9] = wbits;  // final partial word (t=288..299)
  __syncthreads();
  const int WO = WI >> 1;
  const int bc = (int)(inrow0 / (WI * WI));
  const int y0 = (int)((inrow0 % (WI * WI)) / WI);
  const float dd = dly[bc % C];
  const long orow0 = (long)bc * (WO * WO) + (y0 >> 1) * WO;
  for (int i = tid; i < 4800; i += 256) {
    int ro = i / TLEN, t = i - ro * TLEN;
    int Yr = ro / WO, X = ro - Yr * WO;
    int ir = (2 * Yr) * WI + 2 * X;
    float src = (float)t - dd;
    float fi = floorf(src);
    int i0 = (int)fi;
    float wf = src - fi;
    bool ok0 = (i0 >= 0) && (i0 < TLEN);
    bool ok1 = (i0 + 1 >= 0) && (i0 + 1 < TLEN);
    int j0 = min(max(i0, 0), TLEN - 1);
    int j1 = min(max(i0 + 1, 0), TLEN - 1);
    int s0i = 0, s1i = 0;
#pragma unroll
    for (int dy = 0; dy < 2; ++dy)
#pragma unroll
      for (int dx = 0; dx < 2; ++dx) {
        int rr = ir + dy * WI + dx;
        s0i += (int)((bits[rr * 13 + (j0 >> 5)] >> (j0 & 31)) & 1u);
        s1i += (int)((bits[rr * 13 + (j1 >> 5)] >> (j1 & 31)) & 1u);
      }
    float s0 = ok0 ? (float)s0i : 0.f;
    float s1 = ok1 ? (float)s1i : 0.f;
    out[(orow0 + ro) * TLEN + t] = (s0 * (1.f - wf) + s1 * wf) * 2.75f;
  }
}

// ---------------- conv1: 2->16 ch, 5x5, pad 2, 32x32, float4 staging ----------------
__global__ __launch_bounds__(256) void conv1_kernel(const float* __restrict__ in,
                                                    const float* __restrict__ w,
                                                    float* __restrict__ out) {
  __shared__ float xl[11520];  // [c2][dy5][x36][t32]
  const int tid = threadIdx.x;
  const int t0 = blockIdx.x * 32;
  const int y = blockIdx.y;
  const int b = blockIdx.z;
  for (int i = tid; i < 2880; i += 256) {
    int tq = i & 7;
    int rest = i >> 3;
    int xp = rest % 36;
    int r2 = rest / 36;
    int dy = r2 % 5;
    int c = r2 / 5;
    int yy = y + dy - 2, xx = xp - 2, t = t0 + tq * 4;
    float4 v = {0.f, 0.f, 0.f, 0.f};
    if (yy >= 0 && yy < 32 && xx >= 0 && xx < 32 && t < TLEN)
      v = *reinterpret_cast<const float4*>(
          in + ((long)((b * 2 + c) * 32 + yy) * 32 + xx) * TLEN + t);
    *reinterpret_cast<float4*>(&xl[rest * 32 + tq * 4]) = v;
  }
  __syncthreads();
  const int tg = tid & 7;
  const int x = tid >> 3;
  float acc[16][4];
#pragma unroll
  for (int o = 0; o < 16; ++o) { acc[o][0] = acc[o][1] = acc[o][2] = acc[o][3] = 0.f; }
  for (int c = 0; c < 2; ++c)
#pragma unroll
    for (int dy = 0; dy < 5; ++dy)
#pragma unroll
      for (int kx = 0; kx < 5; ++kx) {
        const float4 xv = *reinterpret_cast<const float4*>(
            &xl[((c * 5 + dy) * 36 + x + kx) * 32 + tg * 4]);
        const float* wp = w + (c * 5 + dy) * 5 + kx;
#pragma unroll
        for (int o = 0; o < 16; ++o) {
          float wsc = wp[o * 50];
          acc[o][0] += wsc * xv.x; acc[o][1] += wsc * xv.y;
          acc[o][2] += wsc * xv.z; acc[o][3] += wsc * xv.w;
        }
      }
  const int t = t0 + tg * 4;
  if (t < TLEN) {
#pragma unroll
    for (int o = 0; o < 16; ++o) {
      float4 res; res.x = acc[o][0]; res.y = acc[o][1]; res.z = acc[o][2]; res.w = acc[o][3];
      *reinterpret_cast<float4*>(&out[((long)((b * 16 + o) * 32 + y) * 32 + x) * TLEN + t]) = res;
    }
  }
}

// ---------------- conv2: 16->32 ch, 3x3, pad 1, 16x16, float4 staging ----------------
__global__ __launch_bounds__(256) void conv2_kernel(const float* __restrict__ in,
                                                    const float* __restrict__ w,
                                                    float* __restrict__ out) {
  __shared__ float xl[13824];  // [c16][dy3][x18][t16]
  const int tid = threadIdx.x;
  const int t0 = blockIdx.x * 16;
  const int y = blockIdx.y;
  const int b = blockIdx.z;
  for (int i = tid; i < 3456; i += 256) {
    int tq = i & 3;
    int rest = i >> 2;
    int xp = rest % 18;
    int r2 = rest / 18;
    int dy = r2 % 3;
    int c = r2 / 3;
    int yy = y + dy - 1, xx = xp - 1, t = t0 + tq * 4;
    float4 v = {0.f, 0.f, 0.f, 0.f};
    if (yy >= 0 && yy < 16 && xx >= 0 && xx < 16 && t < TLEN)
      v = *reinterpret_cast<const float4*>(
          in + ((long)((b * 16 + c) * 16 + yy) * 16 + xx) * TLEN + t);
    *reinterpret_cast<float4*>(&xl[rest * 16 + tq * 4]) = v;
  }
  __syncthreads();
  const int tg = tid & 3;
  const int x = (tid >> 2) & 15;
  const int oh = tid >> 6;
  float acc[8][4];
#pragma unroll
  for (int o = 0; o < 8; ++o) { acc[o][0] = acc[o][1] = acc[o][2] = acc[o][3] = 0.f; }
  for (int c = 0; c < 16; ++c)
#pragma unroll
    for (int dy = 0; dy < 3; ++dy)
#pragma unroll
      for (int kx = 0; kx < 3; ++kx) {
        const float4 xv = *reinterpret_cast<const float4*>(
            &xl[((c * 3 + dy) * 18 + x + kx) * 16 + tg * 4]);
        const float* wp = w + (c * 3 + dy) * 3 + kx;
#pragma unroll
        for (int oo = 0; oo < 8; ++oo) {
          float wsc = wp[(oh * 8 + oo) * 144];
          acc[oo][0] += wsc * xv.x; acc[oo][1] += wsc * xv.y;
          acc[oo][2] += wsc * xv.z; acc[oo][3] += wsc * xv.w;
        }
      }
  const int t = t0 + tg * 4;
  if (t < TLEN) {
#pragma unroll
    for (int oo = 0; oo < 8; ++oo) {
      int o = oh * 8 + oo;
      float4 res; res.x = acc[oo][0]; res.y = acc[oo][1]; res.z = acc[oo][2]; res.w = acc[oo][3];
      *reinterpret_cast<float4*>(&out[((long)((b * 32 + o) * 16 + y) * 16 + x) * TLEN + t]) = res;
    }
  }
}

// ---------------- fc1: k-split x4, 64x64 tiles, float4 staging, partials out ----------------
__global__ __launch_bounds__(256) void fc1_kernel(const float* __restrict__ x,
                                                  const float* __restrict__ w,
                                                  float* __restrict__ part) {
  __shared__ float wl[64][44];
  __shared__ float xlb[32][68];
  const int tid = threadIdx.x;
  const int t0 = blockIdx.x * 64;
  const int o0 = blockIdx.y * 64;
  const int b = blockIdx.z >> 2;
  const int split = blockIdx.z & 3;
  const int tx = tid & 15, ty = tid >> 4;
  float acc[4][4];
#pragma unroll
  for (int i = 0; i < 4; ++i)
#pragma unroll
    for (int j = 0; j < 4; ++j) acc[i][j] = 0.f;
  const int kbeg = split * 512;
  for (int kc = kbeg; kc < kbeg + 512; kc += 32) {
    __syncthreads();
#pragma unroll
    for (int rr = 0; rr < 2; ++rr) {
      int i = rr * 256 + tid;
      int ol = i >> 3, kq = i & 7;
      float4 v = *reinterpret_cast<const float4*>(w + (long)(o0 + ol) * 2048 + kc + kq * 4);
      *reinterpret_cast<float4*>(&wl[ol][kq * 4]) = v;
    }
#pragma unroll
    for (int rr = 0; rr < 2; ++rr) {
      int i = rr * 256 + tid;
      int kl = i >> 4, tq = i & 15;
      int t = t0 + tq * 4;
      float4 v = {0.f, 0.f, 0.f, 0.f};
      if (t < TLEN)
        v = *reinterpret_cast<const float4*>(x + ((long)b * 2048 + kc + kl) * TLEN + t);
      *reinterpret_cast<float4*>(&xlb[kl][tq * 4]) = v;
    }
    __syncthreads();
#pragma unroll
    for (int k4 = 0; k4 < 8; ++k4) {
      float4 wq[4], xq[4];
#pragma unroll
      for (int i = 0; i < 4; ++i)
        wq[i] = *reinterpret_cast<const float4*>(&wl[ty * 4 + i][k4 * 4]);
#pragma unroll
      for (int j = 0; j < 4; ++j)
        xq[j] = *reinterpret_cast<const float4*>(&xlb[k4 * 4 + j][tx * 4]);
#pragma unroll
      for (int i = 0; i < 4; ++i) {
        float wa[4] = {wq[i].x, wq[i].y, wq[i].z, wq[i].w};
#pragma unroll
        for (int j = 0; j < 4; ++j) {
          float xa[4] = {xq[j].x, xq[j].y, xq[j].z, xq[j].w};
          acc[i][0] += wa[j] * xa[0]; acc[i][1] += wa[j] * xa[1];
          acc[i][2] += wa[j] * xa[2]; acc[i][3] += wa[j] * xa[3];
        }
      }
    }
  }
  const int t = t0 + tx * 4;
  if (t < TLEN) {
#pragma unroll
    for (int i = 0; i < 4; ++i) {
      float4 res; res.x = acc[i][0]; res.y = acc[i][1]; res.z = acc[i][2]; res.w = acc[i][3];
      *reinterpret_cast<float4*>(
          part + ((long)(split * 4 + b) * 512 + o0 + ty * 4 + i) * TLEN + t) = res;
    }
  }
}

// ---------------- fc2 + final spike scan fused, writes d_out ----------------
__global__ __launch_bounds__(320) void fc2_spike_kernel(const float* __restrict__ x,
                                                        const float* __restrict__ w,
                                                        float* __restrict__ out) {
  __shared__ float ul[304];
  int blk = blockIdx.x;
  int b = blk / 11, o = blk % 11;
  int t = threadIdx.x;
  if (t < TLEN) {
    const float* xr = x + (long)b * 512 * TLEN + t;
    const float* wr = w + o * 512;
    float a0 = 0.f, a1 = 0.f, a2 = 0.f, a3 = 0.f;
#pragma unroll 4
    for (int i = 0; i < 512; i += 4) {
      a0 += wr[i] * xr[(long)i * TLEN];
      a1 += wr[i + 1] * xr[(long)(i + 1) * TLEN];
      a2 += wr[i + 2] * xr[(long)(i + 2) * TLEN];
      a3 += wr[i + 3] * xr[(long)(i + 3) * TLEN];
    }
    ul[t] = (a0 + a1) + (a2 + a3);
  }
  __syncthreads();
  if (t == 0) {
    float ref = 0.f;
#pragma unroll 4
    for (int c = 0; c < TLEN; ++c) {
      float v = ul[c] + ref - THETA;
      float sp = (v >= 0.f) ? 1.f : 0.f;
      ul[c] = sp;
      ref = REF_DECAY * ref - 20.0f * sp;
    }
  }
  __syncthreads();
  if (t < TLEN) out[((long)b * 11 + o) * TLEN + t] = ul[t];
}

extern "C" void kernel_launch(void* const* d_in, const int* in_sizes, int n_in,
                              void* d_out, int out_size, void* d_ws, size_t ws_size,
                              hipStream_t stream) {
  const float* input = (const float*)d_in[0];
  const float* w1    = (const float*)d_in[1];
  const float* w2    = (const float*)d_in[2];
  const float* wfc1  = (const float*)d_in[3];
  const float* wfc2  = (const float*)d_in[4];
  const float* d1    = (const float*)d_in[5];
  const float* d2    = (const float*)d_in[6];
  const float* d3    = (const float*)d_in[7];

  float* ws   = (float*)d_ws;
  float* big0 = ws;                    // conv u (19.66M) / fc1 partials (2.46M)
  float* medA = big0 + 19660800;
  float* medB = medA + 4915200;
  float* fcA  = medB + 4915200;
  float* fcB  = fcA + 614400;
  float* eps  = fcB + 614400;

  hipLaunchKernelGGL(eps_init_kernel, dim3(1), dim3(128), 0, stream, eps);

  // L1: pool4 -> medA; psp -> medB (u); scan; psp -> medA = psp(S0)
  hipLaunchKernelGGL(pool4_kernel, dim3(600), dim3(256), 0, stream, input, medA);
  hipLaunchKernelGGL(fir_direct_kernel, dim3(1216), dim3(256), 0, stream, medA, medB, eps, 8192);
  hipLaunchKernelGGL(scan_kernel, dim3(128), dim3(64), 0, stream, medB, 8192L);
  hipLaunchKernelGGL(fir_direct_kernel, dim3(1216), dim3(256), 0, stream, medB, medA, eps, 8192);
  // L2: conv1 -> u1 (big0); fused spike+pool2+delay1 -> medB
  hipLaunchKernelGGL(conv1_kernel, dim3(10, 32, 4), dim3(256), 0, stream, medA, w1, big0);
  hipLaunchKernelGGL(spike_pool2_delay_kernel, dim3(1024), dim3(256), 0, stream,
                     big0, d1, medB, 32, 16);
  // L3: psp -> medA (u); scan; psp -> medB = psp(S2)
  hipLaunchKernelGGL(fir_direct_kernel, dim3(2432), dim3(256), 0, stream, medB, medA, eps, 16384);
  hipLaunchKernelGGL(scan_kernel, dim3(256), dim3(64), 0, stream, medA, 16384L);
  hipLaunchKernelGGL(fir_direct_kernel, dim3(2432), dim3(256), 0, stream, medA, medB, eps, 16384);
  // L4: conv2 -> u3 (big0); fused spike+pool2+delay2 -> medA
  hipLaunchKernelGGL(conv2_kernel, dim3(19, 16, 4), dim3(256), 0, stream, medB, w2, big0);
  hipLaunchKernelGGL(spike_pool2_delay_kernel, dim3(512), dim3(256), 0, stream,
                     big0, d2, medA, 16, 32);
  // L5: psp -> medB (u); scan; psp -> medA = psp(S4)
  hipLaunchKernelGGL(fir_direct_kernel, dim3(1216), dim3(256), 0, stream, medA, medB, eps, 8192);
  hipLaunchKernelGGL(scan_kernel, dim3(128), dim3(64), 0, stream, medB, 8192L);
  hipLaunchKernelGGL(fir_direct_kernel, dim3(1216), dim3(256), 0, stream, medB, medA, eps, 8192);
  // L6: fc1 -> partials (big0); sum+scan -> S5 (fcA)
  hipLaunchKernelGGL(fc1_kernel, dim3(5, 8, 16), dim3(256), 0, stream, medA, wfc1, big0);
  hipLaunchKernelGGL(scan_reduce4_kernel, dim3(32), dim3(64), 0, stream, big0, fcA);
  // L7: delay3 -> fcB; psp -> fcA; fc2+spike -> d_out
  hipLaunchKernelGGL(delay_kernel, dim3(2400), dim3(256), 0, stream, fcA, d3, fcB, 614400);
  hipLaunchKernelGGL(fir_direct_kernel, dim3(304), dim3(256), 0, stream, fcB, fcA, eps, 2048);
  hipLaunchKernelGGL(fc2_spike_kernel, dim3(44), dim3(320), 0, stream, fcA, wfc2, (float*)d_out);
}